// Round 3
// baseline (256.643 us; speedup 1.0000x reference)
//
#include <hip/hip_runtime.h>

#define PI_D 3.14159265358979323846
#define NS 128
#define NVOX (NS*NS*NS)
#define NBLK (NVOX/256)

// LDS atlas box budget (voxels); 13*8*13*10 floats = 54.1 KB
#define BX 13
#define BY 8
#define BZ 13

// ---------- device helpers ----------

static __device__ __forceinline__ float bspline3f(float t) {
    t = fabsf(t);
    if (t < 1.0f) return (4.0f - 6.0f*t*t + 3.0f*t*t*t) * (1.0f/6.0f);
    if (t < 2.0f) { float u = 2.0f - t; return u*u*u * (1.0f/6.0f); }
    return 0.0f;
}

static __device__ void mm4(const double* Am, const double* Bm, double* Cm) {
    for (int i = 0; i < 4; i++)
        for (int j = 0; j < 4; j++) {
            double s = 0.0;
            for (int k = 0; k < 4; k++) s += Am[i*4+k] * Bm[k*4+j];
            Cm[i*4+j] = s;
        }
}

static __device__ void inv4(const double* Am, double* Om) {
    double a[4][8];
    for (int i = 0; i < 4; i++)
        for (int j = 0; j < 4; j++) {
            a[i][j]   = Am[i*4+j];
            a[i][4+j] = (i == j) ? 1.0 : 0.0;
        }
    for (int col = 0; col < 4; col++) {
        int piv = col; double best = fabs(a[col][col]);
        for (int r = col+1; r < 4; r++) {
            double v = fabs(a[r][col]);
            if (v > best) { best = v; piv = r; }
        }
        if (piv != col)
            for (int j = 0; j < 8; j++) { double t = a[col][j]; a[col][j] = a[piv][j]; a[piv][j] = t; }
        double d = a[col][col];
        for (int j = 0; j < 8; j++) a[col][j] /= d;
        for (int r = 0; r < 4; r++) if (r != col) {
            double f = a[r][col];
            for (int j = 0; j < 8; j++) a[r][j] -= f * a[col][j];
        }
    }
    for (int i = 0; i < 4; i++)
        for (int j = 0; j < 4; j++) Om[i*4+j] = a[i][4+j];
}

// ---------- ws layout ----------
// floats:
// [0..15]    V (4x4 row-major)
// [16]       def_pen
// [17..29]   rw[g]   = weights[g]/sqrt(2*pi*vars[g])
// [32..44]   niv[g]  = -0.5/vars[g]
// [48..60]   mus[g]
// [64..1599] spline weights: [a*128+i]*4+k  (a=axis, 16B-aligned per i)
// ints at float idx 1600: spline indices, same layout (1536 ints)
// doubles at byte 16384: per-block partials [NBLK]  (ends at 81920)
// floats at byte 131072: tB[128][128][13][3]  (2.56 MB separable field intermediate)

__global__ void AD_prep(const float* __restrict__ aff_I, const float* __restrict__ aff_A,
                        const float* __restrict__ ts, const float* __restrict__ thetas,
                        const float* __restrict__ scalings, const float* __restrict__ shears,
                        const float* __restrict__ FIELD,
                        const float* __restrict__ vars_, const float* __restrict__ weights,
                        const float* __restrict__ mus,
                        float* __restrict__ wsf, int* __restrict__ wsi)
{
    const int tid = threadIdx.x;

    if (tid == 0) {
        double c0 = cos((double)thetas[0]*(PI_D/180.0)), s0 = sin((double)thetas[0]*(PI_D/180.0));
        double c1 = cos((double)thetas[1]*(PI_D/180.0)), s1 = sin((double)thetas[1]*(PI_D/180.0));
        double c2 = cos((double)thetas[2]*(PI_D/180.0)), s2 = sin((double)thetas[2]*(PI_D/180.0));
        double Rx[16] = {1,0,0,0,  0,c0,-s0,0,  0,s0,c0,0,  0,0,0,1};
        double Ry[16] = {c1,0,s1,0,  0,1,0,0,  -s1,0,c1,0,  0,0,0,1};
        double Rz[16] = {c2,-s2,0,0,  s2,c2,0,0,  0,0,1,0,  0,0,0,1};
        double t1[16], t2[16];
        mm4(Ry, Rx, t1);
        mm4(Rz, t1, t2);                 // t2 = Rz Ry Rx
        double sc0 = exp((double)scalings[0]/20.0);
        double sc1 = exp((double)scalings[1]/20.0);
        double sc2 = exp((double)scalings[2]/20.0);
        for (int j = 0; j < 4; j++) { t2[0*4+j] *= sc0; t2[1*4+j] *= sc1; t2[2*4+j] *= sc2; }
        double sh0 = (double)shears[0]/100.0, sh1 = (double)shears[1]/100.0, sh2 = (double)shears[2]/100.0;
        double Sh[16] = {1,sh1,sh2,0,  sh0,1,sh2,0,  sh0,sh1,1,0,  0,0,0,1};
        mm4(Sh, t2, t1);                 // t1 = Sh Sc Rz Ry Rx
        t1[3]  += (double)ts[0];
        t1[7]  += (double)ts[1];
        t1[11] += (double)ts[2];
        double Aa[16]; for (int i = 0; i < 16; i++) Aa[i] = (double)aff_A[i];
        mm4(t1, Aa, t2);                 // M = AFF @ aff_A
        double Mi[16]; inv4(t2, Mi);
        double Ai[16]; for (int i = 0; i < 16; i++) Ai[i] = (double)aff_I[i];
        mm4(Mi, Ai, t1);                 // V
        for (int i = 0; i < 16; i++) wsf[i] = (float)t1[i];
    }

    if (tid < 13) {
        float va = vars_[tid];
        wsf[17+tid] = weights[tid] / sqrtf(6.283185307179586f * va);
        wsf[32+tid] = -0.5f / va;
        wsf[48+tid] = mus[tid];
    }

    if (tid < 128) {
        for (int a = 0; a < 3; a++) {
            float coord = (13.0f * (float)(2*tid)) / 256.0f;
            int base = (int)floorf(coord);
            for (int k = 0; k < 4; k++) {
                int node = base + (k - 1);
                float w = bspline3f(coord - (float)node);
                int idx = node % 13; if (idx < 0) idx += 13;
                wsf[64 + (a*128+tid)*4 + k] = w;
                wsi[(a*128+tid)*4 + k] = idx;
            }
        }
    }

    // def_pen reduction (fv = FIELD * {0.08125, 0.0975, 0.08125})
    __shared__ double red[256];
    double s = 0.0;
    for (int i = tid; i < 12*13*13*3; i += 256) {
        int d = i % 3; int r = i / 3; int cc = r % 13; r /= 13; int b = r % 13; int a = r / 13;
        float sf = (d == 1) ? 0.0975f : 0.08125f;
        float f1 = FIELD[(((a+1)*13+b)*13+cc)*3+d] * sf;
        float f0 = FIELD[(((a  )*13+b)*13+cc)*3+d] * sf;
        float df = f1 - f0; s += (double)(df*df);
    }
    for (int i = tid; i < 13*12*13*3; i += 256) {
        int d = i % 3; int r = i / 3; int cc = r % 13; r /= 13; int b = r % 12; int a = r / 12;
        float sf = (d == 1) ? 0.0975f : 0.08125f;
        float f1 = FIELD[((a*13+(b+1))*13+cc)*3+d] * sf;
        float f0 = FIELD[((a*13+(b  ))*13+cc)*3+d] * sf;
        float df = f1 - f0; s += (double)(df*df);
    }
    for (int i = tid; i < 13*13*12*3; i += 256) {
        int d = i % 3; int r = i / 3; int cc = r % 12; r /= 12; int b = r % 13; int a = r / 13;
        float sf = (d == 1) ? 0.0975f : 0.08125f;
        float f1 = FIELD[((a*13+b)*13+(cc+1))*3+d] * sf;
        float f0 = FIELD[((a*13+b)*13+(cc  ))*3+d] * sf;
        float df = f1 - f0; s += (double)(df*df);
    }
    red[tid] = s; __syncthreads();
    for (int st = 128; st > 0; st >>= 1) {
        if (tid < st) red[tid] += red[tid+st];
        __syncthreads();
    }
    if (tid == 0) wsf[16] = (float)(0.01 * red[0] / (6084.0 * 3.0));
}

// tB[i][j][c][d] = sum_a sum_b Wx[i,a] Wy[j,b] field_f[a,b,c,d]
__global__ void AD_field(const float* __restrict__ FIELD,
                         const float* __restrict__ wsf, const int* __restrict__ wsi,
                         float* __restrict__ tB)
{
    __shared__ float fld[13*13*13*3];
    const int tid = threadIdx.x;
    for (int i = tid; i < 13*13*13*3; i += 256) {
        int d = i - (i/3)*3;
        float sc = (d == 1) ? 1.92f : 1.6f;   // field_f = FIELD/100 * {160,192,160}
        fld[i] = FIELD[i] * sc;
    }
    __syncthreads();

    const int p = blockIdx.x*256 + tid;      // 0..16383
    const int j = p & 127, i = p >> 7;

    const float4 wx = *(const float4*)(wsf + 64 + (0*128+i)*4);
    const float4 wy = *(const float4*)(wsf + 64 + (1*128+j)*4);
    const int4  ix4 = *(const int4*)(wsi + (0*128+i)*4);
    const int4  iy4 = *(const int4*)(wsi + (1*128+j)*4);
    const float wxa[4] = {wx.x, wx.y, wx.z, wx.w};
    const float wya[4] = {wy.x, wy.y, wy.z, wy.w};
    const int   ixa[4] = {ix4.x, ix4.y, ix4.z, ix4.w};
    const int   iya[4] = {iy4.x, iy4.y, iy4.z, iy4.w};

    float acc[39];
    #pragma unroll
    for (int t = 0; t < 39; t++) acc[t] = 0.f;

    #pragma unroll
    for (int a = 0; a < 4; a++) {
        #pragma unroll
        for (int b = 0; b < 4; b++) {
            const float wab = wxa[a] * wya[b];
            const float* src = fld + (ixa[a]*13 + iya[b]) * 39;
            #pragma unroll
            for (int t = 0; t < 39; t++) acc[t] = fmaf(wab, src[t], acc[t]);
        }
    }
    float* dst = tB + (size_t)p * 39;
    #pragma unroll
    for (int t = 0; t < 39; t++) dst[t] = acc[t];
}

// Block = 8x4x8 voxel brick (x,y,z). Stage the block's atlas bounding box in
// LDS, gather trilinear taps from LDS. Fallback to global gather if the box
// exceeds the LDS budget (block-uniform, data-deterministic).
__launch_bounds__(256)
__global__ void AD_main(const float* __restrict__ I, const float* __restrict__ A,
                        const float* __restrict__ wsf, const int* __restrict__ wsi,
                        const float* __restrict__ tB,
                        double* __restrict__ partials, float* __restrict__ out)
{
    __shared__ float box[BX*BY*BZ*10];   // 54.1 KB
    __shared__ float tbrow[32*40];       // 5.1 KB
    __shared__ double wred[4];
    __shared__ int mm[6];                // min x,y,z ; max x,y,z

    const int tid = threadIdx.x;
    const int bid = blockIdx.x;
    const int tz = bid & 15, ty = (bid >> 4) & 31, tx = bid >> 9;

    // stage this block's 32 tB rows (reg-staged, unrolled)
    {
        float tr[5];
        #pragma unroll
        for (int k = 0; k < 5; k++) {
            int i = k*256 + tid;
            if (i < 32*39) {
                int r = i / 39, o = i - r*39;
                tr[k] = tB[(size_t)((tx*8 + (r>>2))*128 + ty*4 + (r&3))*39 + o];
            }
        }
        if (tid < 3) mm[tid] = 0x7fffffff;
        else if (tid < 6) mm[tid] = 0;
        #pragma unroll
        for (int k = 0; k < 5; k++) {
            int i = k*256 + tid;
            if (i < 32*39) {
                int r = i / 39, o = i - r*39;
                tbrow[r*40 + o] = tr[k];
            }
        }
    }
    __syncthreads();

    const int dz = tid & 7, dy = (tid >> 3) & 3, dxv = tid >> 5;
    const int x = tx*8 + dxv, y = ty*4 + dy, z = tz*8 + dz;
    const int v = (x << 14) + (y << 7) + z;

    // 4-tap z B-spline over staged tB row (arithmetic identical to R2)
    const float4 wzv = *(const float4*)(wsf + 64 + (2*128+z)*4);
    const int4  izv = *(const int4*)(wsi + (2*128+z)*4);
    const float* myrow = tbrow + (dxv*4 + dy)*40;

    float fr0, fr1, fr2;
    {
        const float* r0 = myrow + izv.x*3;
        const float* r1 = myrow + izv.y*3;
        const float* r2 = myrow + izv.z*3;
        const float* r3 = myrow + izv.w*3;
        fr0 = wzv.x*r0[0] + wzv.y*r1[0] + wzv.z*r2[0] + wzv.w*r3[0];
        fr1 = wzv.x*r0[1] + wzv.y*r1[1] + wzv.z*r2[1] + wzv.w*r3[1];
        fr2 = wzv.x*r0[2] + wzv.y*r1[2] + wzv.z*r2[2] + wzv.w*r3[2];
    }

    const float X = (float)(2*x), Yf = (float)(2*y), Zf = (float)(2*z);
    const float gx = wsf[0]*X + wsf[1]*Yf + wsf[2]*Zf  + wsf[3]  + fr0;
    const float gy = wsf[4]*X + wsf[5]*Yf + wsf[6]*Zf  + wsf[7]  + fr1;
    const float gz = wsf[8]*X + wsf[9]*Yf + wsf[10]*Zf + wsf[11] + fr2;

    float* grids = out + 1;
    __builtin_nontemporal_store(gx, grids + (size_t)v*3 + 0);
    __builtin_nontemporal_store(gy, grids + (size_t)v*3 + 1);
    __builtin_nontemporal_store(gz, grids + (size_t)v*3 + 2);

    // trilinear taps (validity folded into per-axis weights)
    const float x0f = floorf(gx), y0f = floorf(gy), z0f = floorf(gz);
    const int x0 = (int)x0f, y0 = (int)y0f, z0 = (int)z0f;
    const float rx = gx - x0f, ry = gy - y0f, rz = gz - z0f;

    int lx[2], ly[2], lz[2]; float wxt[2], wyt[2], wzt[2];
    lx[0] = x0   < 0 ? 0 : (x0   > 159 ? 159 : x0);
    lx[1] = x0+1 < 0 ? 0 : (x0+1 > 159 ? 159 : x0+1);
    ly[0] = y0   < 0 ? 0 : (y0   > 191 ? 191 : y0);
    ly[1] = y0+1 < 0 ? 0 : (y0+1 > 191 ? 191 : y0+1);
    lz[0] = z0   < 0 ? 0 : (z0   > 159 ? 159 : z0);
    lz[1] = z0+1 < 0 ? 0 : (z0+1 > 159 ? 159 : z0+1);
    wxt[0] = (x0   >= 0 && x0   < 160) ? (1.f - rx) : 0.f;
    wxt[1] = (x0+1 >= 0 && x0+1 < 160) ? rx : 0.f;
    wyt[0] = (y0   >= 0 && y0   < 192) ? (1.f - ry) : 0.f;
    wyt[1] = (y0+1 >= 0 && y0+1 < 192) ? ry : 0.f;
    wzt[0] = (z0   >= 0 && z0   < 160) ? (1.f - rz) : 0.f;
    wzt[1] = (z0+1 >= 0 && z0+1 < 160) ? rz : 0.f;

    // block bounding box: wave butterfly min/max, then shared atomics
    {
        int a0 = lx[0], a1 = ly[0], a2 = lz[0], a3 = lx[1], a4 = ly[1], a5 = lz[1];
        #pragma unroll
        for (int off = 32; off > 0; off >>= 1) {
            a0 = min(a0, __shfl_xor(a0, off, 64));
            a1 = min(a1, __shfl_xor(a1, off, 64));
            a2 = min(a2, __shfl_xor(a2, off, 64));
            a3 = max(a3, __shfl_xor(a3, off, 64));
            a4 = max(a4, __shfl_xor(a4, off, 64));
            a5 = max(a5, __shfl_xor(a5, off, 64));
        }
        if ((tid & 63) == 0) {
            atomicMin(&mm[0], a0); atomicMin(&mm[1], a1); atomicMin(&mm[2], a2);
            atomicMax(&mm[3], a3); atomicMax(&mm[4], a4); atomicMax(&mm[5], a5);
        }
    }
    __syncthreads();

    const int x0b = mm[0], y0b = mm[1], z0b = mm[2];
    const int sx = mm[3] - x0b + 1, sy = mm[4] - y0b + 1, sz = mm[5] - z0b + 1;

    float acc[10];
    #pragma unroll
    for (int c = 0; c < 10; c++) acc[c] = 0.f;

    const float2* A2 = (const float2*)A;

    if (sx <= BX && sy <= BY && sz <= BZ) {
        // ---- stage box into LDS (reg-staged, 8-deep) ----
        const int rn2 = sz * 5;              // float2 per (x,y) row
        const int n2  = sx * sy * rn2;
        float2* lds2 = (float2*)box;
        for (int ibase = 0; ibase < n2; ibase += 256*8) {
            float2 r[8];
            #pragma unroll
            for (int k = 0; k < 8; k++) {
                int i = ibase + k*256 + tid;
                if (i < n2) {
                    int row = i / rn2, o = i - row*rn2;
                    int bx = row / sy, by = row - bx*sy;
                    r[k] = A2[(size_t)(((x0b+bx)*192 + (y0b+by))*160 + z0b)*5 + o];
                }
            }
            #pragma unroll
            for (int k = 0; k < 8; k++) {
                int i = ibase + k*256 + tid;
                if (i < n2) lds2[i] = r[k];
            }
        }
        __syncthreads();

        // ---- gather from LDS ----
        const float2* lds2c = (const float2*)box;
        #pragma unroll
        for (int ta = 0; ta < 2; ta++) {
            #pragma unroll
            for (int tb = 0; tb < 2; tb++) {
                const float wab = wxt[ta] * wyt[tb];
                const int rowb = ((lx[ta]-x0b)*sy + (ly[tb]-y0b))*sz - z0b;
                #pragma unroll
                for (int tc = 0; tc < 2; tc++) {
                    const float w = wab * wzt[tc];
                    const float2* p = lds2c + (size_t)(rowb + lz[tc])*5;
                    #pragma unroll
                    for (int h = 0; h < 5; h++) {
                        float2 t = p[h];
                        acc[2*h]   = fmaf(w, t.x, acc[2*h]);
                        acc[2*h+1] = fmaf(w, t.y, acc[2*h+1]);
                    }
                }
            }
        }
    } else {
        // ---- fallback: direct global gather (R2 path) ----
        #pragma unroll
        for (int ta = 0; ta < 2; ta++) {
            #pragma unroll
            for (int tb = 0; tb < 2; tb++) {
                const float wab = wxt[ta] * wyt[tb];
                const size_t rowb = (size_t)(lx[ta]*192 + ly[tb]) * 160;
                #pragma unroll
                for (int tc = 0; tc < 2; tc++) {
                    const float w = wab * wzt[tc];
                    const float2* p = A2 + (rowb + lz[tc])*5;
                    #pragma unroll
                    for (int h = 0; h < 5; h++) {
                        float2 t = p[h];
                        acc[2*h]   = fmaf(w, t.x, acc[2*h]);
                        acc[2*h+1] = fmaf(w, t.y, acc[2*h+1]);
                    }
                }
            }
        }
    }

    // priors
    float pri[10]; float sum = 0.f;
    #pragma unroll
    for (int c = 0; c < 10; c++) {
        float t = acc[c]; t = t < 0.f ? 0.f : (t > 1.f ? 1.f : t);
        pri[c] = t; sum += t;
    }
    float p0 = pri[0] + (1.0f - sum);
    pri[0] = p0 < 0.f ? 0.f : (p0 > 1.f ? 1.f : p0);

    float* priors = out + 1 + (size_t)NVOX*3 + (size_t)v*10;
    #pragma unroll
    for (int c = 0; c < 10; c++) __builtin_nontemporal_store(pri[c], priors + c);

    // GMM likelihood; cls = repeat(arange(9), COMPS), COMPS={2,2,1,1,2,1,1,2,1}
    const float Iv = __builtin_nontemporal_load(I + ((size_t)(2*x)*256 + (size_t)(2*y))*256 + (size_t)(2*z));
    const float gl_bg = expf(-0.005f*Iv*Iv) * 0.039894228040143274f;  // 1/sqrt(2*pi*100)

    constexpr int CLS[13] = {0,0,1,1,2,3,4,4,5,6,7,7,8};
    float lh[9];
    #pragma unroll
    for (int c = 0; c < 9; c++) lh[c] = 0.f;
    #pragma unroll
    for (int g = 0; g < 13; g++) {
        const float dlt = Iv - wsf[48+g];
        lh[CLS[g]] += wsf[17+g] * expf(dlt*dlt*wsf[32+g]);
    }
    float nrm = pri[0] * gl_bg;
    #pragma unroll
    for (int c = 0; c < 9; c++) nrm = fmaf(pri[c+1], lh[c], nrm);
    const float ll = logf(1e-9f + nrm);

    // deterministic reduction
    double s = (double)ll;
    #pragma unroll
    for (int off = 32; off > 0; off >>= 1) s += __shfl_down(s, off, 64);
    if ((tid & 63) == 0) wred[tid >> 6] = s;
    __syncthreads();
    if (tid == 0) partials[blockIdx.x] = (wred[0] + wred[1]) + (wred[2] + wred[3]);
}

__global__ void AD_fin(const double* __restrict__ partials, const float* __restrict__ wsf,
                       float* __restrict__ out, int out_size)
{
    __shared__ double red[256];
    const int tid = threadIdx.x;
    double s = 0.0;
    for (int i = tid; i < NBLK; i += 256) s += partials[i];
    red[tid] = s; __syncthreads();
    for (int st = 128; st > 0; st >>= 1) {
        if (tid < st) red[tid] += red[tid+st];
        __syncthreads();
    }
    if (tid == 0) {
        float dp = wsf[16];
        out[0] = (float)(-(red[0] / (double)NVOX) + (double)dp);
        out[out_size-1] = dp;
    }
}

extern "C" void kernel_launch(void* const* d_in, const int* in_sizes, int n_in,
                              void* d_out, int out_size, void* d_ws, size_t ws_size,
                              hipStream_t stream)
{
    const float* I        = (const float*)d_in[0];
    const float* A        = (const float*)d_in[1];
    const float* aff_I    = (const float*)d_in[2];
    const float* aff_A    = (const float*)d_in[3];
    const float* mus      = (const float*)d_in[4];
    const float* vars_    = (const float*)d_in[5];
    const float* weights  = (const float*)d_in[6];
    const float* ts       = (const float*)d_in[8];
    const float* thetas   = (const float*)d_in[9];
    const float* scalings = (const float*)d_in[10];
    const float* shears   = (const float*)d_in[11];
    const float* FIELD    = (const float*)d_in[12];

    float* out = (float*)d_out;
    float* wsf = (float*)d_ws;
    int*   wsi = (int*)(wsf + 1600);
    double* partials = (double*)((char*)d_ws + 16384);
    float* tB = (float*)((char*)d_ws + 131072);

    hipLaunchKernelGGL(AD_prep, dim3(1), dim3(256), 0, stream,
                       aff_I, aff_A, ts, thetas, scalings, shears, FIELD, vars_, weights, mus, wsf, wsi);
    hipLaunchKernelGGL(AD_field, dim3(64), dim3(256), 0, stream,
                       FIELD, wsf, wsi, tB);
    hipLaunchKernelGGL(AD_main, dim3(NBLK), dim3(256), 0, stream,
                       I, A, wsf, wsi, tB, partials, out);
    hipLaunchKernelGGL(AD_fin, dim3(1), dim3(256), 0, stream,
                       partials, wsf, out, out_size);
}

// Round 4
// 129.047 us; speedup vs baseline: 1.9888x; 1.9888x over previous
//
#include <hip/hip_runtime.h>

#define PI_D 3.14159265358979323846
#define NS 128
#define NVOX (NS*NS*NS)
#define NBLK (NVOX/256)

// 4-float vector with relaxed (8B) alignment: AMDGPU emits global_load_dwordx4
// for dword-aligned addresses; atlas voxel rows are 40B-strided (8B-aligned).
typedef float f4v __attribute__((ext_vector_type(4)));
typedef f4v f4u __attribute__((aligned(8)));

// ---------- device helpers ----------

static __device__ __forceinline__ float bspline3f(float t) {
    t = fabsf(t);
    if (t < 1.0f) return (4.0f - 6.0f*t*t + 3.0f*t*t*t) * (1.0f/6.0f);
    if (t < 2.0f) { float u = 2.0f - t; return u*u*u * (1.0f/6.0f); }
    return 0.0f;
}

static __device__ void mm4(const double* Am, const double* Bm, double* Cm) {
    for (int i = 0; i < 4; i++)
        for (int j = 0; j < 4; j++) {
            double s = 0.0;
            for (int k = 0; k < 4; k++) s += Am[i*4+k] * Bm[k*4+j];
            Cm[i*4+j] = s;
        }
}

static __device__ void inv4(const double* Am, double* Om) {
    double a[4][8];
    for (int i = 0; i < 4; i++)
        for (int j = 0; j < 4; j++) {
            a[i][j]   = Am[i*4+j];
            a[i][4+j] = (i == j) ? 1.0 : 0.0;
        }
    for (int col = 0; col < 4; col++) {
        int piv = col; double best = fabs(a[col][col]);
        for (int r = col+1; r < 4; r++) {
            double v = fabs(a[r][col]);
            if (v > best) { best = v; piv = r; }
        }
        if (piv != col)
            for (int j = 0; j < 8; j++) { double t = a[col][j]; a[col][j] = a[piv][j]; a[piv][j] = t; }
        double d = a[col][col];
        for (int j = 0; j < 8; j++) a[col][j] /= d;
        for (int r = 0; r < 4; r++) if (r != col) {
            double f = a[r][col];
            for (int j = 0; j < 8; j++) a[r][j] -= f * a[col][j];
        }
    }
    for (int i = 0; i < 4; i++)
        for (int j = 0; j < 4; j++) Om[i*4+j] = a[i][4+j];
}

// ---------- ws layout ----------
// floats:
// [0..15]    V (4x4 row-major)
// [16]       def_pen
// [17..29]   rw[g]   = weights[g]/sqrt(2*pi*vars[g])
// [32..44]   niv[g]  = -0.5/vars[g]
// [48..60]   mus[g]
// [64..1599] spline weights: [a*128+i]*4+k  (a=axis, 16B-aligned per i)
// ints at float idx 1600: spline indices, same layout (1536 ints)
// doubles at byte 16384: per-block partials [NBLK]  (ends at 81920)
// floats at byte 131072: tB[128][128][13][3]  (2.56 MB separable field intermediate)

__global__ void AD_prep(const float* __restrict__ aff_I, const float* __restrict__ aff_A,
                        const float* __restrict__ ts, const float* __restrict__ thetas,
                        const float* __restrict__ scalings, const float* __restrict__ shears,
                        const float* __restrict__ FIELD,
                        const float* __restrict__ vars_, const float* __restrict__ weights,
                        const float* __restrict__ mus,
                        float* __restrict__ wsf, int* __restrict__ wsi)
{
    const int tid = threadIdx.x;

    if (tid == 0) {
        double c0 = cos((double)thetas[0]*(PI_D/180.0)), s0 = sin((double)thetas[0]*(PI_D/180.0));
        double c1 = cos((double)thetas[1]*(PI_D/180.0)), s1 = sin((double)thetas[1]*(PI_D/180.0));
        double c2 = cos((double)thetas[2]*(PI_D/180.0)), s2 = sin((double)thetas[2]*(PI_D/180.0));
        double Rx[16] = {1,0,0,0,  0,c0,-s0,0,  0,s0,c0,0,  0,0,0,1};
        double Ry[16] = {c1,0,s1,0,  0,1,0,0,  -s1,0,c1,0,  0,0,0,1};
        double Rz[16] = {c2,-s2,0,0,  s2,c2,0,0,  0,0,1,0,  0,0,0,1};
        double t1[16], t2[16];
        mm4(Ry, Rx, t1);
        mm4(Rz, t1, t2);                 // t2 = Rz Ry Rx
        double sc0 = exp((double)scalings[0]/20.0);
        double sc1 = exp((double)scalings[1]/20.0);
        double sc2 = exp((double)scalings[2]/20.0);
        for (int j = 0; j < 4; j++) { t2[0*4+j] *= sc0; t2[1*4+j] *= sc1; t2[2*4+j] *= sc2; }
        double sh0 = (double)shears[0]/100.0, sh1 = (double)shears[1]/100.0, sh2 = (double)shears[2]/100.0;
        double Sh[16] = {1,sh1,sh2,0,  sh0,1,sh2,0,  sh0,sh1,1,0,  0,0,0,1};
        mm4(Sh, t2, t1);                 // t1 = Sh Sc Rz Ry Rx
        t1[3]  += (double)ts[0];
        t1[7]  += (double)ts[1];
        t1[11] += (double)ts[2];
        double Aa[16]; for (int i = 0; i < 16; i++) Aa[i] = (double)aff_A[i];
        mm4(t1, Aa, t2);                 // M = AFF @ aff_A
        double Mi[16]; inv4(t2, Mi);
        double Ai[16]; for (int i = 0; i < 16; i++) Ai[i] = (double)aff_I[i];
        mm4(Mi, Ai, t1);                 // V
        for (int i = 0; i < 16; i++) wsf[i] = (float)t1[i];
    }

    if (tid < 13) {
        float va = vars_[tid];
        wsf[17+tid] = weights[tid] / sqrtf(6.283185307179586f * va);
        wsf[32+tid] = -0.5f / va;
        wsf[48+tid] = mus[tid];
    }

    if (tid < 128) {
        for (int a = 0; a < 3; a++) {
            float coord = (13.0f * (float)(2*tid)) / 256.0f;
            int base = (int)floorf(coord);
            for (int k = 0; k < 4; k++) {
                int node = base + (k - 1);
                float w = bspline3f(coord - (float)node);
                int idx = node % 13; if (idx < 0) idx += 13;
                wsf[64 + (a*128+tid)*4 + k] = w;
                wsi[(a*128+tid)*4 + k] = idx;
            }
        }
    }

    // def_pen reduction (fv = FIELD * {0.08125, 0.0975, 0.08125})
    __shared__ double red[256];
    double s = 0.0;
    for (int i = tid; i < 12*13*13*3; i += 256) {
        int d = i % 3; int r = i / 3; int cc = r % 13; r /= 13; int b = r % 13; int a = r / 13;
        float sf = (d == 1) ? 0.0975f : 0.08125f;
        float f1 = FIELD[(((a+1)*13+b)*13+cc)*3+d] * sf;
        float f0 = FIELD[(((a  )*13+b)*13+cc)*3+d] * sf;
        float df = f1 - f0; s += (double)(df*df);
    }
    for (int i = tid; i < 13*12*13*3; i += 256) {
        int d = i % 3; int r = i / 3; int cc = r % 13; r /= 13; int b = r % 12; int a = r / 12;
        float sf = (d == 1) ? 0.0975f : 0.08125f;
        float f1 = FIELD[((a*13+(b+1))*13+cc)*3+d] * sf;
        float f0 = FIELD[((a*13+(b  ))*13+cc)*3+d] * sf;
        float df = f1 - f0; s += (double)(df*df);
    }
    for (int i = tid; i < 13*13*12*3; i += 256) {
        int d = i % 3; int r = i / 3; int cc = r % 12; r /= 12; int b = r % 13; int a = r / 13;
        float sf = (d == 1) ? 0.0975f : 0.08125f;
        float f1 = FIELD[((a*13+b)*13+(cc+1))*3+d] * sf;
        float f0 = FIELD[((a*13+b)*13+(cc  ))*3+d] * sf;
        float df = f1 - f0; s += (double)(df*df);
    }
    red[tid] = s; __syncthreads();
    for (int st = 128; st > 0; st >>= 1) {
        if (tid < st) red[tid] += red[tid+st];
        __syncthreads();
    }
    if (tid == 0) wsf[16] = (float)(0.01 * red[0] / (6084.0 * 3.0));
}

// tB[i][j][c][d] = sum_a sum_b Wx[i,a] Wy[j,b] field_f[a,b,c,d]
__global__ void AD_field(const float* __restrict__ FIELD,
                         const float* __restrict__ wsf, const int* __restrict__ wsi,
                         float* __restrict__ tB)
{
    __shared__ float fld[13*13*13*3];
    const int tid = threadIdx.x;
    for (int i = tid; i < 13*13*13*3; i += 256) {
        int d = i - (i/3)*3;
        float sc = (d == 1) ? 1.92f : 1.6f;   // field_f = FIELD/100 * {160,192,160}
        fld[i] = FIELD[i] * sc;
    }
    __syncthreads();

    const int p = blockIdx.x*256 + tid;      // 0..16383
    const int j = p & 127, i = p >> 7;

    const float4 wx = *(const float4*)(wsf + 64 + (0*128+i)*4);
    const float4 wy = *(const float4*)(wsf + 64 + (1*128+j)*4);
    const int4  ix4 = *(const int4*)(wsi + (0*128+i)*4);
    const int4  iy4 = *(const int4*)(wsi + (1*128+j)*4);
    const float wxa[4] = {wx.x, wx.y, wx.z, wx.w};
    const float wya[4] = {wy.x, wy.y, wy.z, wy.w};
    const int   ixa[4] = {ix4.x, ix4.y, ix4.z, ix4.w};
    const int   iya[4] = {iy4.x, iy4.y, iy4.z, iy4.w};

    float acc[39];
    #pragma unroll
    for (int t = 0; t < 39; t++) acc[t] = 0.f;

    #pragma unroll
    for (int a = 0; a < 4; a++) {
        #pragma unroll
        for (int b = 0; b < 4; b++) {
            const float wab = wxa[a] * wya[b];
            const float* src = fld + (ixa[a]*13 + iya[b]) * 39;
            #pragma unroll
            for (int t = 0; t < 39; t++) acc[t] = fmaf(wab, src[t], acc[t]);
        }
    }
    float* dst = tB + (size_t)p * 39;
    #pragma unroll
    for (int t = 0; t < 39; t++) dst[t] = acc[t];
}

__launch_bounds__(256)
__global__ void AD_main(const float* __restrict__ I, const float* __restrict__ A,
                        const float* __restrict__ wsf, const int* __restrict__ wsi,
                        const float* __restrict__ tB,
                        double* __restrict__ partials, float* __restrict__ out)
{
    __shared__ float sh[80];
    __shared__ double wred[4];
    const int tid = threadIdx.x;

    // block covers two consecutive (x,y) rows
    {
        const float* src = tB + (size_t)(blockIdx.x * 2) * 39;
        if (tid < 78) sh[tid] = src[tid];
    }
    __syncthreads();

    const int v = blockIdx.x*256 + tid;
    const int z = v & 127, y = (v >> 7) & 127, x = v >> 14;

    // 4-tap z B-spline over precomputed tB row
    const float4 wzv = *(const float4*)(wsf + 64 + (2*128+z)*4);
    const int4  izv = *(const int4*)(wsi + (2*128+z)*4);
    const float* myrow = sh + (tid >> 7) * 39;

    float fr0, fr1, fr2;
    {
        const float* r0 = myrow + izv.x*3;
        const float* r1 = myrow + izv.y*3;
        const float* r2 = myrow + izv.z*3;
        const float* r3 = myrow + izv.w*3;
        fr0 = wzv.x*r0[0] + wzv.y*r1[0] + wzv.z*r2[0] + wzv.w*r3[0];
        fr1 = wzv.x*r0[1] + wzv.y*r1[1] + wzv.z*r2[1] + wzv.w*r3[1];
        fr2 = wzv.x*r0[2] + wzv.y*r1[2] + wzv.z*r2[2] + wzv.w*r3[2];
    }

    const float X = (float)(2*x), Yf = (float)(2*y), Zf = (float)(2*z);
    const float gx = wsf[0]*X + wsf[1]*Yf + wsf[2]*Zf  + wsf[3]  + fr0;
    const float gy = wsf[4]*X + wsf[5]*Yf + wsf[6]*Zf  + wsf[7]  + fr1;
    const float gz = wsf[8]*X + wsf[9]*Yf + wsf[10]*Zf + wsf[11] + fr2;

    float* grids = out + 1;
    __builtin_nontemporal_store(gx, grids + (size_t)v*3 + 0);
    __builtin_nontemporal_store(gy, grids + (size_t)v*3 + 1);
    __builtin_nontemporal_store(gz, grids + (size_t)v*3 + 2);

    // trilinear 10-channel atlas sample; z-tap pair merged into 5 dwordx4 loads
    const float x0f = floorf(gx), y0f = floorf(gy), z0f = floorf(gz);
    const int x0 = (int)x0f, y0 = (int)y0f, z0 = (int)z0f;
    const float rx = gx - x0f, ry = gy - y0f, rz = gz - z0f;

    int lx[2], ly[2]; float wxt[2], wyt[2], wzt[2];
    lx[0] = x0   < 0 ? 0 : (x0   > 159 ? 159 : x0);
    lx[1] = x0+1 < 0 ? 0 : (x0+1 > 159 ? 159 : x0+1);
    ly[0] = y0   < 0 ? 0 : (y0   > 191 ? 191 : y0);
    ly[1] = y0+1 < 0 ? 0 : (y0+1 > 191 ? 191 : y0+1);
    wxt[0] = (x0   >= 0 && x0   < 160) ? (1.f - rx) : 0.f;
    wxt[1] = (x0+1 >= 0 && x0+1 < 160) ? rx : 0.f;
    wyt[0] = (y0   >= 0 && y0   < 192) ? (1.f - ry) : 0.f;
    wyt[1] = (y0+1 >= 0 && y0+1 < 192) ? ry : 0.f;
    wzt[0] = (z0   >= 0 && z0   < 160) ? (1.f - rz) : 0.f;
    wzt[1] = (z0+1 >= 0 && z0+1 < 160) ? rz : 0.f;

    const int zb = z0 < 0 ? 0 : (z0 > 158 ? 158 : z0);   // merged-pair base
    const bool hi0 = (z0 >= 159);   // tap-z0 value comes from zb+1
    const bool lo1 = (z0 < 0);      // tap-z1 value comes from zb

    float acc[10];
    #pragma unroll
    for (int c = 0; c < 10; c++) acc[c] = 0.f;

    #pragma unroll
    for (int ta = 0; ta < 2; ta++) {
        #pragma unroll
        for (int tb = 0; tb < 2; tb++) {
            const float wab = wxt[ta] * wyt[tb];
            const float w0 = wab * wzt[0];
            const float w1 = wab * wzt[1];
            const f4u* p = (const f4u*)(A + ((size_t)(lx[ta]*192 + ly[tb])*160 + zb)*10);
            const f4v L0 = p[0], L1 = p[1], L2 = p[2], L3 = p[3], L4 = p[4];
            const float lo[10] = {L0.x,L0.y,L0.z,L0.w, L1.x,L1.y,L1.z,L1.w, L2.x,L2.y};
            const float hiv[10] = {L2.z,L2.w, L3.x,L3.y,L3.z,L3.w, L4.x,L4.y,L4.z,L4.w};
            #pragma unroll
            for (int c = 0; c < 10; c++) {
                const float t0 = hi0 ? hiv[c] : lo[c];
                const float t1 = lo1 ? lo[c]  : hiv[c];
                acc[c] = fmaf(w0, t0, acc[c]);
                acc[c] = fmaf(w1, t1, acc[c]);
            }
        }
    }

    // priors
    float pri[10]; float sum = 0.f;
    #pragma unroll
    for (int c = 0; c < 10; c++) {
        float t = acc[c]; t = t < 0.f ? 0.f : (t > 1.f ? 1.f : t);
        pri[c] = t; sum += t;
    }
    float p0 = pri[0] + (1.0f - sum);
    pri[0] = p0 < 0.f ? 0.f : (p0 > 1.f ? 1.f : p0);

    float* priors = out + 1 + (size_t)NVOX*3 + (size_t)v*10;
    #pragma unroll
    for (int c = 0; c < 10; c++) __builtin_nontemporal_store(pri[c], priors + c);

    // GMM likelihood; cls = repeat(arange(9), COMPS), COMPS={2,2,1,1,2,1,1,2,1}
    const float Iv = __builtin_nontemporal_load(I + ((size_t)(2*x)*256 + (size_t)(2*y))*256 + (size_t)(2*z));
    const float gl_bg = expf(-0.005f*Iv*Iv) * 0.039894228040143274f;  // 1/sqrt(2*pi*100)

    constexpr int CLS[13] = {0,0,1,1,2,3,4,4,5,6,7,7,8};
    float lh[9];
    #pragma unroll
    for (int c = 0; c < 9; c++) lh[c] = 0.f;
    #pragma unroll
    for (int g = 0; g < 13; g++) {
        const float dlt = Iv - wsf[48+g];
        lh[CLS[g]] += wsf[17+g] * expf(dlt*dlt*wsf[32+g]);
    }
    float nrm = pri[0] * gl_bg;
    #pragma unroll
    for (int c = 0; c < 9; c++) nrm = fmaf(pri[c+1], lh[c], nrm);
    const float ll = logf(1e-9f + nrm);

    // deterministic reduction
    double s = (double)ll;
    #pragma unroll
    for (int off = 32; off > 0; off >>= 1) s += __shfl_down(s, off, 64);
    if ((tid & 63) == 0) wred[tid >> 6] = s;
    __syncthreads();
    if (tid == 0) partials[blockIdx.x] = (wred[0] + wred[1]) + (wred[2] + wred[3]);
}

__global__ void AD_fin(const double* __restrict__ partials, const float* __restrict__ wsf,
                       float* __restrict__ out, int out_size)
{
    __shared__ double red[256];
    const int tid = threadIdx.x;
    double s = 0.0;
    for (int i = tid; i < NBLK; i += 256) s += partials[i];
    red[tid] = s; __syncthreads();
    for (int st = 128; st > 0; st >>= 1) {
        if (tid < st) red[tid] += red[tid+st];
        __syncthreads();
    }
    if (tid == 0) {
        float dp = wsf[16];
        out[0] = (float)(-(red[0] / (double)NVOX) + (double)dp);
        out[out_size-1] = dp;
    }
}

extern "C" void kernel_launch(void* const* d_in, const int* in_sizes, int n_in,
                              void* d_out, int out_size, void* d_ws, size_t ws_size,
                              hipStream_t stream)
{
    const float* I        = (const float*)d_in[0];
    const float* A        = (const float*)d_in[1];
    const float* aff_I    = (const float*)d_in[2];
    const float* aff_A    = (const float*)d_in[3];
    const float* mus      = (const float*)d_in[4];
    const float* vars_    = (const float*)d_in[5];
    const float* weights  = (const float*)d_in[6];
    const float* ts       = (const float*)d_in[8];
    const float* thetas   = (const float*)d_in[9];
    const float* scalings = (const float*)d_in[10];
    const float* shears   = (const float*)d_in[11];
    const float* FIELD    = (const float*)d_in[12];

    float* out = (float*)d_out;
    float* wsf = (float*)d_ws;
    int*   wsi = (int*)(wsf + 1600);
    double* partials = (double*)((char*)d_ws + 16384);
    float* tB = (float*)((char*)d_ws + 131072);

    hipLaunchKernelGGL(AD_prep, dim3(1), dim3(256), 0, stream,
                       aff_I, aff_A, ts, thetas, scalings, shears, FIELD, vars_, weights, mus, wsf, wsi);
    hipLaunchKernelGGL(AD_field, dim3(64), dim3(256), 0, stream,
                       FIELD, wsf, wsi, tB);
    hipLaunchKernelGGL(AD_main, dim3(NBLK), dim3(256), 0, stream,
                       I, A, wsf, wsi, tB, partials, out);
    hipLaunchKernelGGL(AD_fin, dim3(1), dim3(256), 0, stream,
                       partials, wsf, out, out_size);
}

// Round 5
// 116.765 us; speedup vs baseline: 2.1980x; 1.1052x over previous
//
#include <hip/hip_runtime.h>

#define PI_D 3.14159265358979323846
#define NS 128
#define NVOX (NS*NS*NS)
#define NBLK (NVOX/256)

// 4-float vector with relaxed (8B) alignment: AMDGPU emits global_load_dwordx4
// for dword-aligned addresses; atlas voxel rows are 40B-strided (8B-aligned).
typedef float f4v __attribute__((ext_vector_type(4)));
typedef f4v f4u __attribute__((aligned(8)));
// dword-aligned float4 for output stores (out+1 base is only 4B-aligned)
typedef float f4s __attribute__((ext_vector_type(4), aligned(4)));

// ---------- device helpers ----------

static __device__ __forceinline__ float bspline3f(float t) {
    t = fabsf(t);
    if (t < 1.0f) return (4.0f - 6.0f*t*t + 3.0f*t*t*t) * (1.0f/6.0f);
    if (t < 2.0f) { float u = 2.0f - t; return u*u*u * (1.0f/6.0f); }
    return 0.0f;
}

static __device__ void mm4(const double* Am, const double* Bm, double* Cm) {
    for (int i = 0; i < 4; i++)
        for (int j = 0; j < 4; j++) {
            double s = 0.0;
            for (int k = 0; k < 4; k++) s += Am[i*4+k] * Bm[k*4+j];
            Cm[i*4+j] = s;
        }
}

static __device__ void inv4(const double* Am, double* Om) {
    double a[4][8];
    for (int i = 0; i < 4; i++)
        for (int j = 0; j < 4; j++) {
            a[i][j]   = Am[i*4+j];
            a[i][4+j] = (i == j) ? 1.0 : 0.0;
        }
    for (int col = 0; col < 4; col++) {
        int piv = col; double best = fabs(a[col][col]);
        for (int r = col+1; r < 4; r++) {
            double v = fabs(a[r][col]);
            if (v > best) { best = v; piv = r; }
        }
        if (piv != col)
            for (int j = 0; j < 8; j++) { double t = a[col][j]; a[col][j] = a[piv][j]; a[piv][j] = t; }
        double d = a[col][col];
        for (int j = 0; j < 8; j++) a[col][j] /= d;
        for (int r = 0; r < 4; r++) if (r != col) {
            double f = a[r][col];
            for (int j = 0; j < 8; j++) a[r][j] -= f * a[col][j];
        }
    }
    for (int i = 0; i < 4; i++)
        for (int j = 0; j < 4; j++) Om[i*4+j] = a[i][4+j];
}

// ---------- ws layout ----------
// floats:
// [0..15]    V (4x4 row-major)
// [16]       def_pen
// [17..29]   rw[g]   = weights[g]/sqrt(2*pi*vars[g])
// [32..44]   niv[g]  = -0.5/vars[g]
// [48..60]   mus[g]
// [64..1599] spline weights: [a*128+i]*4+k  (a=axis, 16B-aligned per i)
// ints at float idx 1600: spline indices, same layout (1536 ints)
// doubles at byte 16384: per-block partials [NBLK]  (ends at 81920)
// floats at byte 131072: tB[128][128][13][3]  (2.56 MB separable field intermediate)

__global__ void AD_prep(const float* __restrict__ aff_I, const float* __restrict__ aff_A,
                        const float* __restrict__ ts, const float* __restrict__ thetas,
                        const float* __restrict__ scalings, const float* __restrict__ shears,
                        const float* __restrict__ FIELD,
                        const float* __restrict__ vars_, const float* __restrict__ weights,
                        const float* __restrict__ mus,
                        float* __restrict__ wsf, int* __restrict__ wsi)
{
    const int tid = threadIdx.x;

    if (tid == 0) {
        double c0 = cos((double)thetas[0]*(PI_D/180.0)), s0 = sin((double)thetas[0]*(PI_D/180.0));
        double c1 = cos((double)thetas[1]*(PI_D/180.0)), s1 = sin((double)thetas[1]*(PI_D/180.0));
        double c2 = cos((double)thetas[2]*(PI_D/180.0)), s2 = sin((double)thetas[2]*(PI_D/180.0));
        double Rx[16] = {1,0,0,0,  0,c0,-s0,0,  0,s0,c0,0,  0,0,0,1};
        double Ry[16] = {c1,0,s1,0,  0,1,0,0,  -s1,0,c1,0,  0,0,0,1};
        double Rz[16] = {c2,-s2,0,0,  s2,c2,0,0,  0,0,1,0,  0,0,0,1};
        double t1[16], t2[16];
        mm4(Ry, Rx, t1);
        mm4(Rz, t1, t2);                 // t2 = Rz Ry Rx
        double sc0 = exp((double)scalings[0]/20.0);
        double sc1 = exp((double)scalings[1]/20.0);
        double sc2 = exp((double)scalings[2]/20.0);
        for (int j = 0; j < 4; j++) { t2[0*4+j] *= sc0; t2[1*4+j] *= sc1; t2[2*4+j] *= sc2; }
        double sh0 = (double)shears[0]/100.0, sh1 = (double)shears[1]/100.0, sh2 = (double)shears[2]/100.0;
        double Sh[16] = {1,sh1,sh2,0,  sh0,1,sh2,0,  sh0,sh1,1,0,  0,0,0,1};
        mm4(Sh, t2, t1);                 // t1 = Sh Sc Rz Ry Rx
        t1[3]  += (double)ts[0];
        t1[7]  += (double)ts[1];
        t1[11] += (double)ts[2];
        double Aa[16]; for (int i = 0; i < 16; i++) Aa[i] = (double)aff_A[i];
        mm4(t1, Aa, t2);                 // M = AFF @ aff_A
        double Mi[16]; inv4(t2, Mi);
        double Ai[16]; for (int i = 0; i < 16; i++) Ai[i] = (double)aff_I[i];
        mm4(Mi, Ai, t1);                 // V
        for (int i = 0; i < 16; i++) wsf[i] = (float)t1[i];
    }

    if (tid < 13) {
        float va = vars_[tid];
        wsf[17+tid] = weights[tid] / sqrtf(6.283185307179586f * va);
        wsf[32+tid] = -0.5f / va;
        wsf[48+tid] = mus[tid];
    }

    if (tid < 128) {
        for (int a = 0; a < 3; a++) {
            float coord = (13.0f * (float)(2*tid)) / 256.0f;
            int base = (int)floorf(coord);
            for (int k = 0; k < 4; k++) {
                int node = base + (k - 1);
                float w = bspline3f(coord - (float)node);
                int idx = node % 13; if (idx < 0) idx += 13;
                wsf[64 + (a*128+tid)*4 + k] = w;
                wsi[(a*128+tid)*4 + k] = idx;
            }
        }
    }

    // def_pen reduction (fv = FIELD * {0.08125, 0.0975, 0.08125})
    __shared__ double red[256];
    double s = 0.0;
    for (int i = tid; i < 12*13*13*3; i += 256) {
        int d = i % 3; int r = i / 3; int cc = r % 13; r /= 13; int b = r % 13; int a = r / 13;
        float sf = (d == 1) ? 0.0975f : 0.08125f;
        float f1 = FIELD[(((a+1)*13+b)*13+cc)*3+d] * sf;
        float f0 = FIELD[(((a  )*13+b)*13+cc)*3+d] * sf;
        float df = f1 - f0; s += (double)(df*df);
    }
    for (int i = tid; i < 13*12*13*3; i += 256) {
        int d = i % 3; int r = i / 3; int cc = r % 13; r /= 13; int b = r % 12; int a = r / 12;
        float sf = (d == 1) ? 0.0975f : 0.08125f;
        float f1 = FIELD[((a*13+(b+1))*13+cc)*3+d] * sf;
        float f0 = FIELD[((a*13+(b  ))*13+cc)*3+d] * sf;
        float df = f1 - f0; s += (double)(df*df);
    }
    for (int i = tid; i < 13*13*12*3; i += 256) {
        int d = i % 3; int r = i / 3; int cc = r % 12; r /= 12; int b = r % 13; int a = r / 13;
        float sf = (d == 1) ? 0.0975f : 0.08125f;
        float f1 = FIELD[((a*13+b)*13+(cc+1))*3+d] * sf;
        float f0 = FIELD[((a*13+b)*13+(cc  ))*3+d] * sf;
        float df = f1 - f0; s += (double)(df*df);
    }
    red[tid] = s; __syncthreads();
    for (int st = 128; st > 0; st >>= 1) {
        if (tid < st) red[tid] += red[tid+st];
        __syncthreads();
    }
    if (tid == 0) wsf[16] = (float)(0.01 * red[0] / (6084.0 * 3.0));
}

// tB[i][j][c][d] = sum_a sum_b Wx[i,a] Wy[j,b] field_f[a,b,c,d]
__global__ void AD_field(const float* __restrict__ FIELD,
                         const float* __restrict__ wsf, const int* __restrict__ wsi,
                         float* __restrict__ tB)
{
    __shared__ float fld[13*13*13*3];
    const int tid = threadIdx.x;
    for (int i = tid; i < 13*13*13*3; i += 256) {
        int d = i - (i/3)*3;
        float sc = (d == 1) ? 1.92f : 1.6f;   // field_f = FIELD/100 * {160,192,160}
        fld[i] = FIELD[i] * sc;
    }
    __syncthreads();

    const int p = blockIdx.x*256 + tid;      // 0..16383
    const int j = p & 127, i = p >> 7;

    const float4 wx = *(const float4*)(wsf + 64 + (0*128+i)*4);
    const float4 wy = *(const float4*)(wsf + 64 + (1*128+j)*4);
    const int4  ix4 = *(const int4*)(wsi + (0*128+i)*4);
    const int4  iy4 = *(const int4*)(wsi + (1*128+j)*4);
    const float wxa[4] = {wx.x, wx.y, wx.z, wx.w};
    const float wya[4] = {wy.x, wy.y, wy.z, wy.w};
    const int   ixa[4] = {ix4.x, ix4.y, ix4.z, ix4.w};
    const int   iya[4] = {iy4.x, iy4.y, iy4.z, iy4.w};

    float acc[39];
    #pragma unroll
    for (int t = 0; t < 39; t++) acc[t] = 0.f;

    #pragma unroll
    for (int a = 0; a < 4; a++) {
        #pragma unroll
        for (int b = 0; b < 4; b++) {
            const float wab = wxa[a] * wya[b];
            const float* src = fld + (ixa[a]*13 + iya[b]) * 39;
            #pragma unroll
            for (int t = 0; t < 39; t++) acc[t] = fmaf(wab, src[t], acc[t]);
        }
    }
    float* dst = tB + (size_t)p * 39;
    #pragma unroll
    for (int t = 0; t < 39; t++) dst[t] = acc[t];
}

__launch_bounds__(256)
__global__ void AD_main(const float* __restrict__ I, const float* __restrict__ A,
                        const float* __restrict__ wsf, const int* __restrict__ wsi,
                        const float* __restrict__ tB,
                        double* __restrict__ partials, float* __restrict__ out)
{
    __shared__ float sh[80];
    __shared__ double wred[4];
    __shared__ __align__(16) float sg[768];    // grids staging (block-contiguous)
    __shared__ __align__(16) float sp[2560];   // priors staging (block-contiguous)
    const int tid = threadIdx.x;

    // XCD-chunked swizzle: dispatch-slot i lands on XCD i%8; give each XCD a
    // contiguous range of row-pair blocks so neighboring tap rows share an L2.
    const int wg = ((blockIdx.x & 7) << 10) + (blockIdx.x >> 3);

    // block covers two consecutive (x,y) rows
    {
        const float* src = tB + (size_t)(wg * 2) * 39;
        if (tid < 78) sh[tid] = src[tid];
    }
    __syncthreads();

    const int v = wg*256 + tid;
    const int z = v & 127, y = (v >> 7) & 127, x = v >> 14;

    // 4-tap z B-spline over precomputed tB row
    const float4 wzv = *(const float4*)(wsf + 64 + (2*128+z)*4);
    const int4  izv = *(const int4*)(wsi + (2*128+z)*4);
    const float* myrow = sh + (tid >> 7) * 39;

    float fr0, fr1, fr2;
    {
        const float* r0 = myrow + izv.x*3;
        const float* r1 = myrow + izv.y*3;
        const float* r2 = myrow + izv.z*3;
        const float* r3 = myrow + izv.w*3;
        fr0 = wzv.x*r0[0] + wzv.y*r1[0] + wzv.z*r2[0] + wzv.w*r3[0];
        fr1 = wzv.x*r0[1] + wzv.y*r1[1] + wzv.z*r2[1] + wzv.w*r3[1];
        fr2 = wzv.x*r0[2] + wzv.y*r1[2] + wzv.z*r2[2] + wzv.w*r3[2];
    }

    const float X = (float)(2*x), Yf = (float)(2*y), Zf = (float)(2*z);
    const float gx = wsf[0]*X + wsf[1]*Yf + wsf[2]*Zf  + wsf[3]  + fr0;
    const float gy = wsf[4]*X + wsf[5]*Yf + wsf[6]*Zf  + wsf[7]  + fr1;
    const float gz = wsf[8]*X + wsf[9]*Yf + wsf[10]*Zf + wsf[11] + fr2;

    sg[tid*3+0] = gx; sg[tid*3+1] = gy; sg[tid*3+2] = gz;

    // trilinear 10-channel atlas sample; z-tap pair merged into 5 dwordx4 loads
    const float x0f = floorf(gx), y0f = floorf(gy), z0f = floorf(gz);
    const int x0 = (int)x0f, y0 = (int)y0f, z0 = (int)z0f;
    const float rx = gx - x0f, ry = gy - y0f, rz = gz - z0f;

    int lx[2], ly[2]; float wxt[2], wyt[2], wzt[2];
    lx[0] = x0   < 0 ? 0 : (x0   > 159 ? 159 : x0);
    lx[1] = x0+1 < 0 ? 0 : (x0+1 > 159 ? 159 : x0+1);
    ly[0] = y0   < 0 ? 0 : (y0   > 191 ? 191 : y0);
    ly[1] = y0+1 < 0 ? 0 : (y0+1 > 191 ? 191 : y0+1);
    wxt[0] = (x0   >= 0 && x0   < 160) ? (1.f - rx) : 0.f;
    wxt[1] = (x0+1 >= 0 && x0+1 < 160) ? rx : 0.f;
    wyt[0] = (y0   >= 0 && y0   < 192) ? (1.f - ry) : 0.f;
    wyt[1] = (y0+1 >= 0 && y0+1 < 192) ? ry : 0.f;
    wzt[0] = (z0   >= 0 && z0   < 160) ? (1.f - rz) : 0.f;
    wzt[1] = (z0+1 >= 0 && z0+1 < 160) ? rz : 0.f;

    const int zb = z0 < 0 ? 0 : (z0 > 158 ? 158 : z0);   // merged-pair base
    const bool hi0 = (z0 >= 159);   // tap-z0 value comes from zb+1
    const bool lo1 = (z0 < 0);      // tap-z1 value comes from zb

    float acc[10];
    #pragma unroll
    for (int c = 0; c < 10; c++) acc[c] = 0.f;

    #pragma unroll
    for (int ta = 0; ta < 2; ta++) {
        #pragma unroll
        for (int tb = 0; tb < 2; tb++) {
            const float wab = wxt[ta] * wyt[tb];
            const float w0 = wab * wzt[0];
            const float w1 = wab * wzt[1];
            const f4u* p = (const f4u*)(A + ((size_t)(lx[ta]*192 + ly[tb])*160 + zb)*10);
            const f4v L0 = p[0], L1 = p[1], L2 = p[2], L3 = p[3], L4 = p[4];
            const float lo[10] = {L0.x,L0.y,L0.z,L0.w, L1.x,L1.y,L1.z,L1.w, L2.x,L2.y};
            const float hiv[10] = {L2.z,L2.w, L3.x,L3.y,L3.z,L3.w, L4.x,L4.y,L4.z,L4.w};
            #pragma unroll
            for (int c = 0; c < 10; c++) {
                const float t0 = hi0 ? hiv[c] : lo[c];
                const float t1 = lo1 ? lo[c]  : hiv[c];
                acc[c] = fmaf(w0, t0, acc[c]);
                acc[c] = fmaf(w1, t1, acc[c]);
            }
        }
    }

    // priors
    float pri[10]; float sum = 0.f;
    #pragma unroll
    for (int c = 0; c < 10; c++) {
        float t = acc[c]; t = t < 0.f ? 0.f : (t > 1.f ? 1.f : t);
        pri[c] = t; sum += t;
    }
    float p0 = pri[0] + (1.0f - sum);
    pri[0] = p0 < 0.f ? 0.f : (p0 > 1.f ? 1.f : p0);

    #pragma unroll
    for (int c = 0; c < 10; c++) sp[tid*10+c] = pri[c];

    // GMM likelihood; cls = repeat(arange(9), COMPS), COMPS={2,2,1,1,2,1,1,2,1}
    const float Iv = __builtin_nontemporal_load(I + ((size_t)(2*x)*256 + (size_t)(2*y))*256 + (size_t)(2*z));
    const float gl_bg = expf(-0.005f*Iv*Iv) * 0.039894228040143274f;  // 1/sqrt(2*pi*100)

    constexpr int CLS[13] = {0,0,1,1,2,3,4,4,5,6,7,7,8};
    float lh[9];
    #pragma unroll
    for (int c = 0; c < 9; c++) lh[c] = 0.f;
    #pragma unroll
    for (int g = 0; g < 13; g++) {
        const float dlt = Iv - wsf[48+g];
        lh[CLS[g]] += wsf[17+g] * expf(dlt*dlt*wsf[32+g]);
    }
    float nrm = pri[0] * gl_bg;
    #pragma unroll
    for (int c = 0; c < 9; c++) nrm = fmaf(pri[c+1], lh[c], nrm);
    const float ll = logf(1e-9f + nrm);

    // deterministic reduction
    double s = (double)ll;
    #pragma unroll
    for (int off = 32; off > 0; off >>= 1) s += __shfl_down(s, off, 64);
    if ((tid & 63) == 0) wred[tid >> 6] = s;
    __syncthreads();   // also makes sg/sp visible block-wide
    if (tid == 0) partials[wg] = (wred[0] + wred[1]) + (wred[2] + wred[3]);

    // coalesced output stores from LDS staging
    {
        const f4s* g4 = (const f4s*)sg;
        f4s* gdst = (f4s*)(out + 1) + (size_t)wg*192;
        if (tid < 192) __builtin_nontemporal_store(g4[tid], gdst + tid);

        const f4s* p4 = (const f4s*)sp;
        f4s* pdst = (f4s*)(out + 1 + (size_t)NVOX*3) + (size_t)wg*640;
        #pragma unroll
        for (int k = 0; k < 3; k++) {
            int j = k*256 + tid;
            if (j < 640) __builtin_nontemporal_store(p4[j], pdst + j);
        }
    }
}

__global__ void AD_fin(const double* __restrict__ partials, const float* __restrict__ wsf,
                       float* __restrict__ out, int out_size)
{
    __shared__ double red[256];
    const int tid = threadIdx.x;
    double s = 0.0;
    for (int i = tid; i < NBLK; i += 256) s += partials[i];
    red[tid] = s; __syncthreads();
    for (int st = 128; st > 0; st >>= 1) {
        if (tid < st) red[tid] += red[tid+st];
        __syncthreads();
    }
    if (tid == 0) {
        float dp = wsf[16];
        out[0] = (float)(-(red[0] / (double)NVOX) + (double)dp);
        out[out_size-1] = dp;
    }
}

extern "C" void kernel_launch(void* const* d_in, const int* in_sizes, int n_in,
                              void* d_out, int out_size, void* d_ws, size_t ws_size,
                              hipStream_t stream)
{
    const float* I        = (const float*)d_in[0];
    const float* A        = (const float*)d_in[1];
    const float* aff_I    = (const float*)d_in[2];
    const float* aff_A    = (const float*)d_in[3];
    const float* mus      = (const float*)d_in[4];
    const float* vars_    = (const float*)d_in[5];
    const float* weights  = (const float*)d_in[6];
    const float* ts       = (const float*)d_in[8];
    const float* thetas   = (const float*)d_in[9];
    const float* scalings = (const float*)d_in[10];
    const float* shears   = (const float*)d_in[11];
    const float* FIELD    = (const float*)d_in[12];

    float* out = (float*)d_out;
    float* wsf = (float*)d_ws;
    int*   wsi = (int*)(wsf + 1600);
    double* partials = (double*)((char*)d_ws + 16384);
    float* tB = (float*)((char*)d_ws + 131072);

    hipLaunchKernelGGL(AD_prep, dim3(1), dim3(256), 0, stream,
                       aff_I, aff_A, ts, thetas, scalings, shears, FIELD, vars_, weights, mus, wsf, wsi);
    hipLaunchKernelGGL(AD_field, dim3(64), dim3(256), 0, stream,
                       FIELD, wsf, wsi, tB);
    hipLaunchKernelGGL(AD_main, dim3(NBLK), dim3(256), 0, stream,
                       I, A, wsf, wsi, tB, partials, out);
    hipLaunchKernelGGL(AD_fin, dim3(1), dim3(256), 0, stream,
                       partials, wsf, out, out_size);
}